// Round 29
// baseline (229.361 us; speedup 1.0000x reference)
//
#include <hip/hip_runtime.h>
#include <hip/hip_bf16.h>
#include <math.h>

#define DIM   384
#define HEADS 12
#define HD    32
#define WIN   7
#define NPIX  49
#define IMG   56
#define NPF   3136
#define NWIN  1024

typedef __attribute__((ext_vector_type(8))) short short8;
typedef __attribute__((ext_vector_type(4))) float f32x4;
typedef __attribute__((ext_vector_type(4))) float f4;
typedef __attribute__((ext_vector_type(4))) unsigned short us4;
typedef __attribute__((ext_vector_type(8))) unsigned short us8;
#define MFMA __builtin_amdgcn_mfma_f32_16x16x32_bf16

#define SOFT_BARRIER()                                         \
  do {                                                         \
    asm volatile("s_waitcnt lgkmcnt(0)" ::: "memory");         \
    __builtin_amdgcn_s_barrier();                              \
  } while (0)

__device__ inline ushort tob(float f) {
  unsigned u; __builtin_memcpy(&u, &f, 4);
  u += 0x7fffu + ((u >> 16) & 1u);
  return (ushort)(u >> 16);
}

// ---------------- bias table (pre-scaled by log2(e) for exp2-softmax) -------
__global__ void k_bias(const float* __restrict__ cpb, float* __restrict__ bias) {
  int idx = blockIdx.x * 256 + threadIdx.x;
  if (idx >= HEADS * NPIX * NPIX) return;
  int m = idx % NPIX;
  int n = (idx / NPIX) % NPIX;
  int h = idx / (NPIX * NPIX);
  int sy = (n / WIN - m / WIN) + (WIN - 1);
  int sx = (n % WIN - m % WIN) + (WIN - 1);
  const double inv_log_beta = 1.0 / log(1.3);
  double fy = (sy == 0 ? 0.0 : log1p((double)sy) * inv_log_beta) + 6.0;
  double fx = (sx == 0 ? 0.0 : log1p((double)sx) * inv_log_beta) + 6.0;
  fy = fmin(12.0, fmax(0.0, fy));
  fx = fmin(12.0, fmax(0.0, fx));
  int ridx = (int)(fy * 13.0 + fx);
  bias[idx] = cpb[ridx * HEADS + h] * 1.4426950408889634f;   // * log2(e)
}

__global__ void k_rmap(int* __restrict__ rmap) {
  int p = blockIdx.x * 256 + threadIdx.x;
  if (p < NPF) {
    int wb = p / NPIX, n = p - (p / NPIX) * NPIX;
    int gy = wb >> 3, gx = wb & 7;
    int wy = n / WIN, wx = n - (n / WIN) * WIN;
    rmap[p] = ((gy * WIN + wy + 4) % IMG) * IMG + (gx * WIN + wx + 4) % IMG;
  }
}

// ---------------- weights -> bf16 (once) ----------------
__global__ void k_wcvt(const float* __restrict__ wqkv, const float* __restrict__ wproj,
                       ushort* __restrict__ wqb, ushort* __restrict__ wpb) {
  int i = blockIdx.x * 256 + threadIdx.x;
  const int nq = 1152 * DIM / 8;
  const int np = DIM * DIM / 8;
  if (i < nq) {
    f4 a = *(const f4*)&wqkv[i * 8];
    f4 b = *(const f4*)&wqkv[i * 8 + 4];
    us8 u; u[0]=tob(a[0]);u[1]=tob(a[1]);u[2]=tob(a[2]);u[3]=tob(a[3]);
    u[4]=tob(b[0]);u[5]=tob(b[1]);u[6]=tob(b[2]);u[7]=tob(b[3]);
    *(us8*)&wqb[i * 8] = u;
  } else if (i < nq + np) {
    int j = i - nq;
    f4 a = *(const f4*)&wproj[j * 8];
    f4 b = *(const f4*)&wproj[j * 8 + 4];
    us8 u; u[0]=tob(a[0]);u[1]=tob(a[1]);u[2]=tob(a[2]);u[3]=tob(a[3]);
    u[4]=tob(b[0]);u[5]=tob(b[1]);u[6]=tob(b[2]);u[7]=tob(b[3]);
    *(us8*)&wpb[j * 8] = u;
  }
}

// ---------------- x -> xw[b][p'][c] bf16, 6-way channel-split ---------------
__global__ __launch_bounds__(256) void k_xw(const float* __restrict__ x,
                                            const int* __restrict__ rmap,
                                            ushort* __restrict__ xw) {
  int gid = blockIdx.x * 256 + threadIdx.x;   // 16*6*3136 exact
  int p  = gid % NPF;
  int cc = (gid / NPF) % 6;
  int b  = gid / (6 * NPF);
  int sp = rmap[p];
  const float* xs = x + (size_t)b * DIM * NPF + (size_t)(cc * 64) * NPF + sp;
  ushort* xd = xw + ((size_t)b * NPF + p) * DIM + cc * 64;
  for (int c0 = 0; c0 < 64; c0 += 8) {
    us8 u;
#pragma unroll
    for (int i = 0; i < 8; ++i) u[i] = tob(xs[(size_t)(c0 + i) * NPF]);
    *(us8*)&xd[c0] = u;
  }
}

// ---------------- QKV GEMM: 128x128, XOR-swizzled unpadded LDS (32 KB) ------
__global__ __launch_bounds__(256) void k_qkv_pm(const ushort* __restrict__ xw,
                                                const ushort* __restrict__ wqb,
                                                ushort* __restrict__ qk,
                                                ushort* __restrict__ vt) {
  __shared__ __align__(16) ushort sA[2][128 * 32];
  __shared__ __align__(16) ushort sB[2][128 * 32];
  int t   = threadIdx.x;
  int bid = blockIdx.x;
  int swz = (bid & 7) * 450 + (bid >> 3);   // 3600 = 8*450, bijective
  int o0  = (swz % 9) * 128;
  int pbt = swz / 9;
  int p0  = (pbt % 25) * 128;
  int b   = pbt / 25;

  int lane = t & 63, w = t >> 6;
  int wm = w >> 1, wn = w & 1;
  int l15 = lane & 15, l4 = lane >> 4;

  // staging: unit u -> row u>>2, global chunk u&3; LDS col = (chunk ^ (row&3))*8
  int ra0 = t >> 2,          c0i = t & 3;
  int ra1 = (t + 256) >> 2;  // chunk same (t&3)
  int ca  = c0i * 8;
  int ac0 = ((c0i ^ (ra0 & 3)) << 3);
  int ac1 = ((c0i ^ (ra1 & 3)) << 3);
  const ushort* apt0 = wqb + (size_t)(o0 + ra0) * DIM + ca;
  const ushort* apt1 = wqb + (size_t)(o0 + ra1) * DIM + ca;
  int pr0 = p0 + ra0; if (pr0 >= NPF) pr0 = NPF - 1;
  int pr1 = p0 + ra1; if (pr1 >= NPF) pr1 = NPF - 1;
  const ushort* bpt0 = xw + ((size_t)b * NPF + pr0) * DIM + ca;
  const ushort* bpt1 = xw + ((size_t)b * NPF + pr1) * DIM + ca;

  // fragment read col swizzle: row&3 == l15&3 for all frags
  int cs = ((l4 ^ (l15 & 3)) << 3);

  struct Stage { us8 a0, a1, b0, b1; };
  Stage st0, st1;

#define QLOAD(S, K0)                                    \
  do {                                                  \
    (S).a0 = *(const us8*)&apt0[(K0)];                  \
    (S).a1 = *(const us8*)&apt1[(K0)];                  \
    (S).b0 = *(const us8*)&bpt0[(K0)];                  \
    (S).b1 = *(const us8*)&bpt1[(K0)];                  \
  } while (0)
#define QWRITE(S, BUF)                                  \
  do {                                                  \
    *(us8*)&sA[(BUF)][ra0 * 32 + ac0] = (S).a0;         \
    *(us8*)&sA[(BUF)][ra1 * 32 + ac1] = (S).a1;         \
    *(us8*)&sB[(BUF)][ra0 * 32 + ac0] = (S).b0;         \
    *(us8*)&sB[(BUF)][ra1 * 32 + ac1] = (S).b1;         \
  } while (0)

  f32x4 acc[4][4] = {};

  QLOAD(st0, 0);
  QWRITE(st0, 0);
  QLOAD(st1, 32);

#pragma unroll
  for (int ks = 0; ks < 12; ++ks) {
    SOFT_BARRIER();
    if (ks < 10) {
      if ((ks & 1) == 0) QLOAD(st0, (ks + 2) * 32);
      else               QLOAD(st1, (ks + 2) * 32);
    }
    int cur = ks & 1;
    short8 af[4], bfr[4];
#pragma unroll
    for (int mi = 0; mi < 4; ++mi)
      af[mi] = *(const short8*)&sA[cur][(wm * 64 + mi * 16 + l15) * 32 + cs];
#pragma unroll
    for (int ni = 0; ni < 4; ++ni)
      bfr[ni] = *(const short8*)&sB[cur][(wn * 64 + ni * 16 + l15) * 32 + cs];
#pragma unroll
    for (int mi = 0; mi < 4; ++mi)
#pragma unroll
      for (int ni = 0; ni < 4; ++ni)
        acc[mi][ni] = MFMA(af[mi], bfr[ni], acc[mi][ni], 0, 0, 0);
    if (ks < 11) {
      if ((ks & 1) == 0) QWRITE(st1, 1);
      else               QWRITE(st0, 0);
    }
  }
#undef QLOAD
#undef QWRITE

  if (o0 < 768) {
#pragma unroll
    for (int mi = 0; mi < 4; ++mi)
#pragma unroll
      for (int ni = 0; ni < 4; ++ni) {
        int p = p0 + wn * 64 + ni * 16 + l15;
        if (p < NPF) {
          us4 u;
#pragma unroll
          for (int r = 0; r < 4; ++r) u[r] = tob(acc[mi][ni][r]);
          *(us4*)&qk[((size_t)b * NPF + p) * 768 + o0 + wm * 64 + mi * 16 + (l4 << 2)] = u;
        }
      }
  } else {
    int c0 = o0 - 768 + wm * 64;
#pragma unroll
    for (int mi = 0; mi < 4; ++mi)
#pragma unroll
      for (int ni = 0; ni < 4; ++ni) {
        int p = p0 + wn * 64 + ni * 16 + l15;
        if (p < NPF) {
#pragma unroll
          for (int r = 0; r < 4; ++r) {
            int c = c0 + mi * 16 + (l4 << 2) + r;
            vt[((size_t)b * DIM + c) * NPF + p] = tob(acc[mi][ni][r]);
          }
        }
      }
  }
}

// ---------------- attention: exp2-softmax, 4 heads/block (r28) --------------
__global__ __launch_bounds__(256) void k_attn_pm(ushort* __restrict__ qk,
                                                 const ushort* __restrict__ vt,
                                                 const float* __restrict__ bias) {
  __shared__ __align__(16) ushort pab[4][64 * 72];   // 36864 B

  int t = threadIdx.x;
  int lane = t & 63, wv = t >> 6;
  int bid = blockIdx.x;
  int swz = (bid & 7) * 384 + (bid >> 3);   // 3072 = 8*384, bijective
  int hg = swz % 3, wb = swz / 3;
  int h = hg * 4 + wv;
  int b = wb >> 6;
  int w49 = (wb & 63) * NPIX;
  ushort* qrow = qk + ((size_t)b * NPF + w49) * 768 + h * HD;
  const ushort* vrow = vt + ((size_t)b * DIM + h * HD) * NPF + w49;
  ushort* pa = pab[wv];

  int l15 = lane & 15, l4 = lane >> 4;

  short8 af[4], bfr[4];
#pragma unroll
  for (int mi = 0; mi < 4; ++mi) {
    int rq = mi * 16 + l15; if (rq > 48) rq = 48;
    af[mi] = *(const short8*)&qrow[(size_t)rq * 768 + l4 * 8];
  }
#pragma unroll
  for (int ni = 0; ni < 4; ++ni) {
    int rk = ni * 16 + l15; if (rk > 48) rk = 48;
    bfr[ni] = *(const short8*)&qrow[(size_t)rk * 768 + DIM + l4 * 8];
  }
  f32x4 acc[4][4] = {};
#pragma unroll
  for (int mi = 0; mi < 4; ++mi)
#pragma unroll
    for (int ni = 0; ni < 4; ++ni)
      acc[mi][ni] = MFMA(af[mi], bfr[ni], acc[mi][ni], 0, 0, 0);

  short8 vf[2][2];
#pragma unroll
  for (int ks = 0; ks < 2; ++ks)
#pragma unroll
    for (int nd = 0; nd < 2; ++nd)
      vf[ks][nd] = *(const short8*)&vrow[(size_t)(nd * 16 + l15) * NPF + ks * 32 + l4 * 8];

  const float c1 = 0.25506807186087050f;   // scale * log2(e)
  const float* bh = bias + h * NPIX * NPIX;
  float sm[16];
#pragma unroll
  for (int mi = 0; mi < 4; ++mi)
#pragma unroll
    for (int r = 0; r < 4; ++r) {
      int n = mi * 16 + (l4 << 2) + r;
      float s = 0.f;
#pragma unroll
      for (int ni = 0; ni < 4; ++ni) {
        int m = ni * 16 + l15;
        float e = (m < NPIX && n < NPIX)
                    ? exp2f(fmaf(acc[mi][ni][r], c1, bh[n * NPIX + m]))
                    : 0.f;
        acc[mi][ni][r] = e;
        s += e;
      }
      sm[mi * 4 + r] = s;
    }
#pragma unroll
  for (int i = 1; i < 16; i <<= 1)
#pragma unroll
    for (int j = 0; j < 16; ++j) sm[j] += __shfl_xor(sm[j], i);

#pragma unroll
  for (int mi = 0; mi < 4; ++mi)
#pragma unroll
    for (int r = 0; r < 4; ++r) {
      float ri = 1.f / sm[mi * 4 + r];
      int n = mi * 16 + (l4 << 2) + r;
#pragma unroll
      for (int ni = 0; ni < 4; ++ni)
        pa[n * 72 + ni * 16 + l15] = tob(acc[mi][ni][r] * ri);
    }

  f32x4 yac[4][2] = {};
#pragma unroll
  for (int ks = 0; ks < 2; ++ks) {
    short8 pf[4];
#pragma unroll
    for (int mi = 0; mi < 4; ++mi) pf[mi] = *(const short8*)&pa[(mi * 16 + l15) * 72 + ks * 32 + l4 * 8];
#pragma unroll
    for (int mi = 0; mi < 4; ++mi)
#pragma unroll
      for (int nd = 0; nd < 2; ++nd)
        yac[mi][nd] = MFMA(pf[mi], vf[ks][nd], yac[mi][nd], 0, 0, 0);
  }

#pragma unroll
  for (int mi = 0; mi < 4; ++mi)
#pragma unroll
    for (int nd = 0; nd < 2; ++nd)
#pragma unroll
      for (int r = 0; r < 4; ++r)
        pa[(mi * 16 + (l4 << 2) + r) * 72 + nd * 16 + l15] = tob(yac[mi][nd][r]);
  asm volatile("s_waitcnt lgkmcnt(0)" ::: "memory");
  if (lane < NPIX) {
#pragma unroll
    for (int s = 0; s < 4; ++s)
      *(us8*)&qrow[(size_t)lane * 768 + s * 8] = *(const us8*)&pa[lane * 72 + s * 8];
  }
}

// ---------------- proj GEMM: XOR-swizzled unpadded LDS (32 KB) --------------
__global__ __launch_bounds__(256) void k_proj_pm(const ushort* __restrict__ qk,
                                                 const ushort* __restrict__ wpb,
                                                 float* __restrict__ out) {
  __shared__ __align__(16) ushort sA[2][128 * 32];
  __shared__ __align__(16) ushort sB[2][128 * 32];
  __shared__ int srm[128];
  int t   = threadIdx.x;
  int bid = blockIdx.x;
  int swz = (bid & 7) * 150 + (bid >> 3);   // 1200 = 8*150
  int o0  = (swz % 3) * 128;
  int pb  = swz / 3;
  int p0  = (pb % 25) * 128;
  int b   = pb / 25;
  if (t < 128) {
    int pg = p0 + t;
    if (pg >= NPF) pg = 0;
    int si = (pg / IMG + 53) % IMG, sj = (pg % IMG + 53) % IMG;
    srm[t] = ((si / WIN) * 8 + sj / WIN) * NPIX + (si % WIN) * WIN + (sj % WIN);
  }
  __syncthreads();

  int lane = t & 63, w = t >> 6;
  int wm = w >> 1, wn = w & 1;
  int l15 = lane & 15, l4 = lane >> 4;

  int ra0 = t >> 2,          c0i = t & 3;
  int ra1 = (t + 256) >> 2;
  int ca  = c0i * 8;
  int ac0 = ((c0i ^ (ra0 & 3)) << 3);
  int ac1 = ((c0i ^ (ra1 & 3)) << 3);
  const ushort* apt0 = wpb + (size_t)(o0 + ra0) * DIM + ca;
  const ushort* apt1 = wpb + (size_t)(o0 + ra1) * DIM + ca;
  const ushort* bpt0 = qk + ((size_t)b * NPF + srm[ra0]) * 768 + ca;
  const ushort* bpt1 = qk + ((size_t)b * NPF + srm[ra1]) * 768 + ca;

  int cs = ((l4 ^ (l15 & 3)) << 3);

  struct Stage { us8 a0, a1, b0, b1; };
  Stage st0, st1;

#define PLOAD(S, K0)                                    \
  do {                                                  \
    (S).a0 = *(const us8*)&apt0[(K0)];                  \
    (S).a1 = *(const us8*)&apt1[(K0)];                  \
    (S).b0 = *(const us8*)&bpt0[(K0)];                  \
    (S).b1 = *(const us8*)&bpt1[(K0)];                  \
  } while (0)
#define PWRITE(S, BUF)                                  \
  do {                                                  \
    *(us8*)&sA[(BUF)][ra0 * 32 + ac0] = (S).a0;         \
    *(us8*)&sA[(BUF)][ra1 * 32 + ac1] = (S).a1;         \
    *(us8*)&sB[(BUF)][ra0 * 32 + ac0] = (S).b0;         \
    *(us8*)&sB[(BUF)][ra1 * 32 + ac1] = (S).b1;         \
  } while (0)

  f32x4 acc[4][4] = {};

  PLOAD(st0, 0);
  PWRITE(st0, 0);
  PLOAD(st1, 32);

#pragma unroll
  for (int ks = 0; ks < 12; ++ks) {
    SOFT_BARRIER();
    if (ks < 10) {
      if ((ks & 1) == 0) PLOAD(st0, (ks + 2) * 32);
      else               PLOAD(st1, (ks + 2) * 32);
    }
    int cur = ks & 1;
    short8 af[4], bfr[4];
#pragma unroll
    for (int mi = 0; mi < 4; ++mi)
      af[mi] = *(const short8*)&sA[cur][(wm * 64 + mi * 16 + l15) * 32 + cs];
#pragma unroll
    for (int ni = 0; ni < 4; ++ni)
      bfr[ni] = *(const short8*)&sB[cur][(wn * 64 + ni * 16 + l15) * 32 + cs];
#pragma unroll
    for (int mi = 0; mi < 4; ++mi)
#pragma unroll
      for (int ni = 0; ni < 4; ++ni)
        acc[mi][ni] = MFMA(af[mi], bfr[ni], acc[mi][ni], 0, 0, 0);
    if (ks < 11) {
      if ((ks & 1) == 0) PWRITE(st1, 1);
      else               PWRITE(st0, 0);
    }
  }
#undef PLOAD
#undef PWRITE

  for (int mi = 0; mi < 4; ++mi)
    for (int ni = 0; ni < 4; ++ni)
      for (int r = 0; r < 4; ++r) {
        int o = o0 + wm * 64 + mi * 16 + (l4 << 2) + r;
        int p = p0 + wn * 64 + ni * 16 + l15;
        if (p < NPF)
          out[((size_t)b * DIM + o) * NPF + p] = acc[mi][ni][r];
      }
}

extern "C" void kernel_launch(void* const* d_in, const int* in_sizes, int n_in,
                              void* d_out, int out_size, void* d_ws, size_t ws_size,
                              hipStream_t stream) {
  const float* x     = (const float*)d_in[0];
  const float* wqkv  = (const float*)d_in[1];
  const float* wproj = (const float*)d_in[2];
  const float* cpb   = (const float*)d_in[3];
  float* out = (float*)d_out;

  char* ws = (char*)d_ws;
  float* bias = (float*)ws;                       // 115248 B
  int*   rmap = (int*)(ws + 115712);              // -> 131072
  ushort* wqb = (ushort*)(ws + 131072);           // 884736 B
  ushort* wpb = (ushort*)(ws + 1015808);          // 294912 B -> 1310720
  const size_t QK_B = (size_t)16 * NPF * 768 * 2; // 77,070,336
  const size_t VT_B = (size_t)16 * DIM * NPF * 2; // 38,535,168
  ushort* qk = (ushort*)(ws + 1310720);
  ushort* vt = (ushort*)(ws + 1310720 + QK_B);
  ushort* xw = (ushort*)(ws + 1310720 + QK_B + VT_B);  // ends 155,451,392 (proven)

  hipLaunchKernelGGL(k_bias, dim3(113), dim3(256), 0, stream, cpb, bias);
  hipLaunchKernelGGL(k_rmap, dim3(13), dim3(256), 0, stream, rmap);
  hipLaunchKernelGGL(k_wcvt, dim3(288), dim3(256), 0, stream, wqkv, wproj, wqb, wpb);
  hipLaunchKernelGGL(k_xw, dim3(1176), dim3(256), 0, stream, x, rmap, xw);
  hipLaunchKernelGGL(k_qkv_pm, dim3(3600), dim3(256), 0, stream, xw, wqb, qk, vt);
  hipLaunchKernelGGL(k_attn_pm, dim3(3072), dim3(256), 0, stream, qk, vt, bias);
  hipLaunchKernelGGL(k_proj_pm, dim3(1200), dim3(256), 0, stream, qk, wpb, out);
}

// Round 30
// 226.062 us; speedup vs baseline: 1.0146x; 1.0146x over previous
//
#include <hip/hip_runtime.h>
#include <hip/hip_bf16.h>
#include <math.h>

#define DIM   384
#define HEADS 12
#define HD    32
#define WIN   7
#define NPIX  49
#define IMG   56
#define NPF   3136
#define NWIN  1024

typedef __attribute__((ext_vector_type(8))) short short8;
typedef __attribute__((ext_vector_type(4))) float f32x4;
typedef __attribute__((ext_vector_type(4))) float f4;
typedef __attribute__((ext_vector_type(4))) unsigned short us4;
typedef __attribute__((ext_vector_type(8))) unsigned short us8;
#define MFMA __builtin_amdgcn_mfma_f32_16x16x32_bf16

#define SOFT_BARRIER()                                         \
  do {                                                         \
    asm volatile("s_waitcnt lgkmcnt(0)" ::: "memory");         \
    __builtin_amdgcn_s_barrier();                              \
  } while (0)

__device__ inline ushort tob(float f) {
  unsigned u; __builtin_memcpy(&u, &f, 4);
  u += 0x7fffu + ((u >> 16) & 1u);
  return (ushort)(u >> 16);
}

// ---------------- bias table (pre-scaled by log2(e) for exp2-softmax) -------
__global__ void k_bias(const float* __restrict__ cpb, float* __restrict__ bias) {
  int idx = blockIdx.x * 256 + threadIdx.x;
  if (idx >= HEADS * NPIX * NPIX) return;
  int m = idx % NPIX;
  int n = (idx / NPIX) % NPIX;
  int h = idx / (NPIX * NPIX);
  int sy = (n / WIN - m / WIN) + (WIN - 1);
  int sx = (n % WIN - m % WIN) + (WIN - 1);
  const double inv_log_beta = 1.0 / log(1.3);
  double fy = (sy == 0 ? 0.0 : log1p((double)sy) * inv_log_beta) + 6.0;
  double fx = (sx == 0 ? 0.0 : log1p((double)sx) * inv_log_beta) + 6.0;
  fy = fmin(12.0, fmax(0.0, fy));
  fx = fmin(12.0, fmax(0.0, fx));
  int ridx = (int)(fy * 13.0 + fx);
  bias[idx] = cpb[ridx * HEADS + h] * 1.4426950408889634f;   // * log2(e)
}

__global__ void k_rmap(int* __restrict__ rmap) {
  int p = blockIdx.x * 256 + threadIdx.x;
  if (p < NPF) {
    int wb = p / NPIX, n = p - (p / NPIX) * NPIX;
    int gy = wb >> 3, gx = wb & 7;
    int wy = n / WIN, wx = n - (n / WIN) * WIN;
    rmap[p] = ((gy * WIN + wy + 4) % IMG) * IMG + (gx * WIN + wx + 4) % IMG;
  }
}

// ---------------- weights -> bf16 (once) ----------------
__global__ void k_wcvt(const float* __restrict__ wqkv, const float* __restrict__ wproj,
                       ushort* __restrict__ wqb, ushort* __restrict__ wpb) {
  int i = blockIdx.x * 256 + threadIdx.x;
  const int nq = 1152 * DIM / 8;
  const int np = DIM * DIM / 8;
  if (i < nq) {
    f4 a = *(const f4*)&wqkv[i * 8];
    f4 b = *(const f4*)&wqkv[i * 8 + 4];
    us8 u; u[0]=tob(a[0]);u[1]=tob(a[1]);u[2]=tob(a[2]);u[3]=tob(a[3]);
    u[4]=tob(b[0]);u[5]=tob(b[1]);u[6]=tob(b[2]);u[7]=tob(b[3]);
    *(us8*)&wqb[i * 8] = u;
  } else if (i < nq + np) {
    int j = i - nq;
    f4 a = *(const f4*)&wproj[j * 8];
    f4 b = *(const f4*)&wproj[j * 8 + 4];
    us8 u; u[0]=tob(a[0]);u[1]=tob(a[1]);u[2]=tob(a[2]);u[3]=tob(a[3]);
    u[4]=tob(b[0]);u[5]=tob(b[1]);u[6]=tob(b[2]);u[7]=tob(b[3]);
    *(us8*)&wpb[j * 8] = u;
  }
}

// ---------------- x -> xw[b][p'][c] bf16, 6-way channel-split ---------------
__global__ __launch_bounds__(256) void k_xw(const float* __restrict__ x,
                                            const int* __restrict__ rmap,
                                            ushort* __restrict__ xw) {
  int gid = blockIdx.x * 256 + threadIdx.x;   // 16*6*3136 exact
  int p  = gid % NPF;
  int cc = (gid / NPF) % 6;
  int b  = gid / (6 * NPF);
  int sp = rmap[p];
  const float* xs = x + (size_t)b * DIM * NPF + (size_t)(cc * 64) * NPF + sp;
  ushort* xd = xw + ((size_t)b * NPF + p) * DIM + cc * 64;
  for (int c0 = 0; c0 < 64; c0 += 8) {
    us8 u;
#pragma unroll
    for (int i = 0; i < 8; ++i) u[i] = tob(xs[(size_t)(c0 + i) * NPF]);
    *(us8*)&xd[c0] = u;
  }
}

// ---------------- QKV GEMM: 128x128 tile; q/k -> qk[b][p][768], v -> vt ------
__global__ __launch_bounds__(256) void k_qkv_pm(const ushort* __restrict__ xw,
                                                const ushort* __restrict__ wqb,
                                                ushort* __restrict__ qk,
                                                ushort* __restrict__ vt) {
  __shared__ __align__(16) ushort sA[2][128 * 40];
  __shared__ __align__(16) ushort sB[2][128 * 40];
  int t   = threadIdx.x;
  int bid = blockIdx.x;
  int swz = (bid & 7) * 450 + (bid >> 3);   // 3600 = 8*450, bijective
  int o0  = (swz % 9) * 128;
  int pbt = swz / 9;
  int p0  = (pbt % 25) * 128;
  int b   = pbt / 25;

  int lane = t & 63, w = t >> 6;
  int wm = w >> 1, wn = w & 1;
  int l15 = lane & 15, l4 = lane >> 4;

  int ra0 = t >> 2,          ca0 = (t & 3) * 8;
  int ra1 = (t + 256) >> 2,  ca1 = ((t + 256) & 3) * 8;
  const ushort* apt0 = wqb + (size_t)(o0 + ra0) * DIM + ca0;
  const ushort* apt1 = wqb + (size_t)(o0 + ra1) * DIM + ca1;
  int pr0 = p0 + ra0; if (pr0 >= NPF) pr0 = NPF - 1;
  int pr1 = p0 + ra1; if (pr1 >= NPF) pr1 = NPF - 1;
  const ushort* bpt0 = xw + ((size_t)b * NPF + pr0) * DIM + ca0;
  const ushort* bpt1 = xw + ((size_t)b * NPF + pr1) * DIM + ca1;

  struct Stage { us8 a0, a1, b0, b1; };
  Stage st0, st1;

#define QLOAD(S, K0)                                    \
  do {                                                  \
    (S).a0 = *(const us8*)&apt0[(K0)];                  \
    (S).a1 = *(const us8*)&apt1[(K0)];                  \
    (S).b0 = *(const us8*)&bpt0[(K0)];                  \
    (S).b1 = *(const us8*)&bpt1[(K0)];                  \
  } while (0)
#define QWRITE(S, BUF)                                  \
  do {                                                  \
    *(us8*)&sA[(BUF)][ra0 * 40 + ca0] = (S).a0;         \
    *(us8*)&sA[(BUF)][ra1 * 40 + ca1] = (S).a1;         \
    *(us8*)&sB[(BUF)][ra0 * 40 + ca0] = (S).b0;         \
    *(us8*)&sB[(BUF)][ra1 * 40 + ca1] = (S).b1;         \
  } while (0)

  f32x4 acc[4][4] = {};

  QLOAD(st0, 0);
  QWRITE(st0, 0);
  QLOAD(st1, 32);

#pragma unroll
  for (int ks = 0; ks < 12; ++ks) {
    SOFT_BARRIER();
    if (ks < 10) {
      if ((ks & 1) == 0) QLOAD(st0, (ks + 2) * 32);
      else               QLOAD(st1, (ks + 2) * 32);
    }
    int cur = ks & 1;
    short8 af[4], bfr[4];
#pragma unroll
    for (int mi = 0; mi < 4; ++mi)
      af[mi] = *(const short8*)&sA[cur][(wm * 64 + mi * 16 + l15) * 40 + l4 * 8];
#pragma unroll
    for (int ni = 0; ni < 4; ++ni)
      bfr[ni] = *(const short8*)&sB[cur][(wn * 64 + ni * 16 + l15) * 40 + l4 * 8];
#pragma unroll
    for (int mi = 0; mi < 4; ++mi)
#pragma unroll
      for (int ni = 0; ni < 4; ++ni)
        acc[mi][ni] = MFMA(af[mi], bfr[ni], acc[mi][ni], 0, 0, 0);
    if (ks < 11) {
      if ((ks & 1) == 0) QWRITE(st1, 1);
      else               QWRITE(st0, 0);
    }
  }
#undef QLOAD
#undef QWRITE

  if (o0 < 768) {
#pragma unroll
    for (int mi = 0; mi < 4; ++mi)
#pragma unroll
      for (int ni = 0; ni < 4; ++ni) {
        int p = p0 + wn * 64 + ni * 16 + l15;
        if (p < NPF) {
          us4 u;
#pragma unroll
          for (int r = 0; r < 4; ++r) u[r] = tob(acc[mi][ni][r]);
          *(us4*)&qk[((size_t)b * NPF + p) * 768 + o0 + wm * 64 + mi * 16 + (l4 << 2)] = u;
        }
      }
  } else {
    int c0 = o0 - 768 + wm * 64;
#pragma unroll
    for (int mi = 0; mi < 4; ++mi)
#pragma unroll
      for (int ni = 0; ni < 4; ++ni) {
        int p = p0 + wn * 64 + ni * 16 + l15;
        if (p < NPF) {
#pragma unroll
          for (int r = 0; r < 4; ++r) {
            int c = c0 + mi * 16 + (l4 << 2) + r;
            vt[((size_t)b * DIM + c) * NPF + p] = tob(acc[mi][ni][r]);
          }
        }
      }
  }
}

// ---------------- attention: exp2-softmax, 4 heads/block --------------------
__global__ __launch_bounds__(256) void k_attn_pm(ushort* __restrict__ qk,
                                                 const ushort* __restrict__ vt,
                                                 const float* __restrict__ bias) {
  __shared__ __align__(16) ushort pab[4][64 * 72];   // 36864 B

  int t = threadIdx.x;
  int lane = t & 63, wv = t >> 6;
  int bid = blockIdx.x;
  int swz = (bid & 7) * 384 + (bid >> 3);   // 3072 = 8*384, bijective
  int hg = swz % 3, wb = swz / 3;
  int h = hg * 4 + wv;
  int b = wb >> 6;
  int w49 = (wb & 63) * NPIX;
  ushort* qrow = qk + ((size_t)b * NPF + w49) * 768 + h * HD;
  const ushort* vrow = vt + ((size_t)b * DIM + h * HD) * NPF + w49;
  ushort* pa = pab[wv];

  int l15 = lane & 15, l4 = lane >> 4;

  short8 af[4], bfr[4];
#pragma unroll
  for (int mi = 0; mi < 4; ++mi) {
    int rq = mi * 16 + l15; if (rq > 48) rq = 48;
    af[mi] = *(const short8*)&qrow[(size_t)rq * 768 + l4 * 8];
  }
#pragma unroll
  for (int ni = 0; ni < 4; ++ni) {
    int rk = ni * 16 + l15; if (rk > 48) rk = 48;
    bfr[ni] = *(const short8*)&qrow[(size_t)rk * 768 + DIM + l4 * 8];
  }
  f32x4 acc[4][4] = {};
#pragma unroll
  for (int mi = 0; mi < 4; ++mi)
#pragma unroll
    for (int ni = 0; ni < 4; ++ni)
      acc[mi][ni] = MFMA(af[mi], bfr[ni], acc[mi][ni], 0, 0, 0);

  short8 vf[2][2];
#pragma unroll
  for (int ks = 0; ks < 2; ++ks)
#pragma unroll
    for (int nd = 0; nd < 2; ++nd)
      vf[ks][nd] = *(const short8*)&vrow[(size_t)(nd * 16 + l15) * NPF + ks * 32 + l4 * 8];

  // exp2-softmax: P = exp2(s*c1 + b2) / sum
  const float c1 = 0.25506807186087050f;   // 0.17677669529663687 * log2(e)
  const float* bh = bias + h * NPIX * NPIX;
  float sm[16];
#pragma unroll
  for (int mi = 0; mi < 4; ++mi)
#pragma unroll
    for (int r = 0; r < 4; ++r) {
      int n = mi * 16 + (l4 << 2) + r;
      float s = 0.f;
#pragma unroll
      for (int ni = 0; ni < 4; ++ni) {
        int m = ni * 16 + l15;
        float e = (m < NPIX && n < NPIX)
                    ? exp2f(fmaf(acc[mi][ni][r], c1, bh[n * NPIX + m]))
                    : 0.f;
        acc[mi][ni][r] = e;
        s += e;
      }
      sm[mi * 4 + r] = s;
    }
#pragma unroll
  for (int i = 1; i < 16; i <<= 1)
#pragma unroll
    for (int j = 0; j < 16; ++j) sm[j] += __shfl_xor(sm[j], i);

#pragma unroll
  for (int mi = 0; mi < 4; ++mi)
#pragma unroll
    for (int r = 0; r < 4; ++r) {
      float ri = 1.f / sm[mi * 4 + r];
      int n = mi * 16 + (l4 << 2) + r;
#pragma unroll
      for (int ni = 0; ni < 4; ++ni)
        pa[n * 72 + ni * 16 + l15] = tob(acc[mi][ni][r] * ri);
    }

  f32x4 yac[4][2] = {};
#pragma unroll
  for (int ks = 0; ks < 2; ++ks) {
    short8 pf[4];
#pragma unroll
    for (int mi = 0; mi < 4; ++mi) pf[mi] = *(const short8*)&pa[(mi * 16 + l15) * 72 + ks * 32 + l4 * 8];
#pragma unroll
    for (int mi = 0; mi < 4; ++mi)
#pragma unroll
      for (int nd = 0; nd < 2; ++nd)
        yac[mi][nd] = MFMA(pf[mi], vf[ks][nd], yac[mi][nd], 0, 0, 0);
  }

#pragma unroll
  for (int mi = 0; mi < 4; ++mi)
#pragma unroll
    for (int nd = 0; nd < 2; ++nd)
#pragma unroll
      for (int r = 0; r < 4; ++r)
        pa[(mi * 16 + (l4 << 2) + r) * 72 + nd * 16 + l15] = tob(yac[mi][nd][r]);
  asm volatile("s_waitcnt lgkmcnt(0)" ::: "memory");
  if (lane < NPIX) {
#pragma unroll
    for (int s = 0; s < 4; ++s)
      *(us8*)&qrow[(size_t)lane * 768 + s * 8] = *(const us8*)&pa[lane * 72 + s * 8];
  }
}

// ---------------- proj GEMM: Y from qk (stride 768) -------------------------
__global__ __launch_bounds__(256) void k_proj_pm(const ushort* __restrict__ qk,
                                                 const ushort* __restrict__ wpb,
                                                 float* __restrict__ out) {
  __shared__ __align__(16) ushort sA[2][128 * 40];
  __shared__ __align__(16) ushort sB[2][128 * 40];
  __shared__ int srm[128];
  int t   = threadIdx.x;
  int bid = blockIdx.x;
  int swz = (bid & 7) * 150 + (bid >> 3);   // 1200 = 8*150
  int o0  = (swz % 3) * 128;
  int pb  = swz / 3;
  int p0  = (pb % 25) * 128;
  int b   = pb / 25;
  if (t < 128) {
    int pg = p0 + t;
    if (pg >= NPF) pg = 0;
    int si = (pg / IMG + 53) % IMG, sj = (pg % IMG + 53) % IMG;
    srm[t] = ((si / WIN) * 8 + sj / WIN) * NPIX + (si % WIN) * WIN + (sj % WIN);
  }
  __syncthreads();

  int lane = t & 63, w = t >> 6;
  int wm = w >> 1, wn = w & 1;
  int l15 = lane & 15, l4 = lane >> 4;

  int ra0 = t >> 2,          ca0 = (t & 3) * 8;
  int ra1 = (t + 256) >> 2,  ca1 = ((t + 256) & 3) * 8;
  const ushort* apt0 = wpb + (size_t)(o0 + ra0) * DIM + ca0;
  const ushort* apt1 = wpb + (size_t)(o0 + ra1) * DIM + ca1;
  const ushort* bpt0 = qk + ((size_t)b * NPF + srm[ra0]) * 768 + ca0;
  const ushort* bpt1 = qk + ((size_t)b * NPF + srm[ra1]) * 768 + ca1;

  struct Stage { us8 a0, a1, b0, b1; };
  Stage st0, st1;

#define PLOAD(S, K0)                                    \
  do {                                                  \
    (S).a0 = *(const us8*)&apt0[(K0)];                  \
    (S).a1 = *(const us8*)&apt1[(K0)];                  \
    (S).b0 = *(const us8*)&bpt0[(K0)];                  \
    (S).b1 = *(const us8*)&bpt1[(K0)];                  \
  } while (0)
#define PWRITE(S, BUF)                                  \
  do {                                                  \
    *(us8*)&sA[(BUF)][ra0 * 40 + ca0] = (S).a0;         \
    *(us8*)&sA[(BUF)][ra1 * 40 + ca1] = (S).a1;         \
    *(us8*)&sB[(BUF)][ra0 * 40 + ca0] = (S).b0;         \
    *(us8*)&sB[(BUF)][ra1 * 40 + ca1] = (S).b1;         \
  } while (0)

  f32x4 acc[4][4] = {};

  PLOAD(st0, 0);
  PWRITE(st0, 0);
  PLOAD(st1, 32);

#pragma unroll
  for (int ks = 0; ks < 12; ++ks) {
    SOFT_BARRIER();
    if (ks < 10) {
      if ((ks & 1) == 0) PLOAD(st0, (ks + 2) * 32);
      else               PLOAD(st1, (ks + 2) * 32);
    }
    int cur = ks & 1;
    short8 af[4], bfr[4];
#pragma unroll
    for (int mi = 0; mi < 4; ++mi)
      af[mi] = *(const short8*)&sA[cur][(wm * 64 + mi * 16 + l15) * 40 + l4 * 8];
#pragma unroll
    for (int ni = 0; ni < 4; ++ni)
      bfr[ni] = *(const short8*)&sB[cur][(wn * 64 + ni * 16 + l15) * 40 + l4 * 8];
#pragma unroll
    for (int mi = 0; mi < 4; ++mi)
#pragma unroll
      for (int ni = 0; ni < 4; ++ni)
        acc[mi][ni] = MFMA(af[mi], bfr[ni], acc[mi][ni], 0, 0, 0);
    if (ks < 11) {
      if ((ks & 1) == 0) PWRITE(st1, 1);
      else               PWRITE(st0, 0);
    }
  }
#undef PLOAD
#undef PWRITE

  for (int mi = 0; mi < 4; ++mi)
    for (int ni = 0; ni < 4; ++ni)
      for (int r = 0; r < 4; ++r) {
        int o = o0 + wm * 64 + mi * 16 + (l4 << 2) + r;
        int p = p0 + wn * 64 + ni * 16 + l15;
        if (p < NPF)
          out[((size_t)b * DIM + o) * NPF + p] = acc[mi][ni][r];
      }
}

extern "C" void kernel_launch(void* const* d_in, const int* in_sizes, int n_in,
                              void* d_out, int out_size, void* d_ws, size_t ws_size,
                              hipStream_t stream) {
  const float* x     = (const float*)d_in[0];
  const float* wqkv  = (const float*)d_in[1];
  const float* wproj = (const float*)d_in[2];
  const float* cpb   = (const float*)d_in[3];
  float* out = (float*)d_out;

  char* ws = (char*)d_ws;
  float* bias = (float*)ws;                       // 115248 B
  int*   rmap = (int*)(ws + 115712);              // -> 131072
  ushort* wqb = (ushort*)(ws + 131072);           // 884736 B
  ushort* wpb = (ushort*)(ws + 1015808);          // 294912 B -> 1310720
  const size_t QK_B = (size_t)16 * NPF * 768 * 2; // 77,070,336
  const size_t VT_B = (size_t)16 * DIM * NPF * 2; // 38,535,168
  ushort* qk = (ushort*)(ws + 1310720);
  ushort* vt = (ushort*)(ws + 1310720 + QK_B);
  ushort* xw = (ushort*)(ws + 1310720 + QK_B + VT_B);  // ends 155,451,392 (proven)

  hipLaunchKernelGGL(k_bias, dim3(113), dim3(256), 0, stream, cpb, bias);
  hipLaunchKernelGGL(k_rmap, dim3(13), dim3(256), 0, stream, rmap);
  hipLaunchKernelGGL(k_wcvt, dim3(288), dim3(256), 0, stream, wqkv, wproj, wqb, wpb);
  hipLaunchKernelGGL(k_xw, dim3(1176), dim3(256), 0, stream, x, rmap, xw);
  hipLaunchKernelGGL(k_qkv_pm, dim3(3600), dim3(256), 0, stream, xw, wqb, qk, vt);
  hipLaunchKernelGGL(k_attn_pm, dim3(3072), dim3(256), 0, stream, qk, vt, bias);
  hipLaunchKernelGGL(k_proj_pm, dim3(1200), dim3(256), 0, stream, qk, wpb, out);
}

// Round 31
// 224.241 us; speedup vs baseline: 1.0228x; 1.0081x over previous
//
#include <hip/hip_runtime.h>
#include <hip/hip_bf16.h>
#include <math.h>

#define DIM   384
#define HEADS 12
#define HD    32
#define WIN   7
#define NPIX  49
#define IMG   56
#define NPF   3136
#define NWIN  1024

typedef __attribute__((ext_vector_type(8))) short short8;
typedef __attribute__((ext_vector_type(4))) float f32x4;
typedef __attribute__((ext_vector_type(4))) float f4;
typedef __attribute__((ext_vector_type(4))) unsigned short us4;
typedef __attribute__((ext_vector_type(8))) unsigned short us8;
#define MFMA __builtin_amdgcn_mfma_f32_16x16x32_bf16

#define SOFT_BARRIER()                                         \
  do {                                                         \
    asm volatile("s_waitcnt lgkmcnt(0)" ::: "memory");         \
    __builtin_amdgcn_s_barrier();                              \
  } while (0)

__device__ inline ushort tob(float f) {
  unsigned u; __builtin_memcpy(&u, &f, 4);
  u += 0x7fffu + ((u >> 16) & 1u);
  return (ushort)(u >> 16);
}

// ---------------- bias table (pre-scaled by log2(e) for exp2-softmax) -------
__global__ void k_bias(const float* __restrict__ cpb, float* __restrict__ bias) {
  int idx = blockIdx.x * 256 + threadIdx.x;
  if (idx >= HEADS * NPIX * NPIX) return;
  int m = idx % NPIX;
  int n = (idx / NPIX) % NPIX;
  int h = idx / (NPIX * NPIX);
  int sy = (n / WIN - m / WIN) + (WIN - 1);
  int sx = (n % WIN - m % WIN) + (WIN - 1);
  const double inv_log_beta = 1.0 / log(1.3);
  double fy = (sy == 0 ? 0.0 : log1p((double)sy) * inv_log_beta) + 6.0;
  double fx = (sx == 0 ? 0.0 : log1p((double)sx) * inv_log_beta) + 6.0;
  fy = fmin(12.0, fmax(0.0, fy));
  fx = fmin(12.0, fmax(0.0, fx));
  int ridx = (int)(fy * 13.0 + fx);
  bias[idx] = cpb[ridx * HEADS + h] * 1.4426950408889634f;   // * log2(e)
}

__global__ void k_rmap(int* __restrict__ rmap) {
  int p = blockIdx.x * 256 + threadIdx.x;
  if (p < NPF) {
    int wb = p / NPIX, n = p - (p / NPIX) * NPIX;
    int gy = wb >> 3, gx = wb & 7;
    int wy = n / WIN, wx = n - (n / WIN) * WIN;
    rmap[p] = ((gy * WIN + wy + 4) % IMG) * IMG + (gx * WIN + wx + 4) % IMG;
  }
}

// ---------------- weights -> bf16 (once) ----------------
__global__ void k_wcvt(const float* __restrict__ wqkv, const float* __restrict__ wproj,
                       ushort* __restrict__ wqb, ushort* __restrict__ wpb) {
  int i = blockIdx.x * 256 + threadIdx.x;
  const int nq = 1152 * DIM / 8;
  const int np = DIM * DIM / 8;
  if (i < nq) {
    f4 a = *(const f4*)&wqkv[i * 8];
    f4 b = *(const f4*)&wqkv[i * 8 + 4];
    us8 u; u[0]=tob(a[0]);u[1]=tob(a[1]);u[2]=tob(a[2]);u[3]=tob(a[3]);
    u[4]=tob(b[0]);u[5]=tob(b[1]);u[6]=tob(b[2]);u[7]=tob(b[3]);
    *(us8*)&wqb[i * 8] = u;
  } else if (i < nq + np) {
    int j = i - nq;
    f4 a = *(const f4*)&wproj[j * 8];
    f4 b = *(const f4*)&wproj[j * 8 + 4];
    us8 u; u[0]=tob(a[0]);u[1]=tob(a[1]);u[2]=tob(a[2]);u[3]=tob(a[3]);
    u[4]=tob(b[0]);u[5]=tob(b[1]);u[6]=tob(b[2]);u[7]=tob(b[3]);
    *(us8*)&wpb[j * 8] = u;
  }
}

// ---------------- x -> xw[b][p'][c] bf16, 6-way channel-split ---------------
__global__ __launch_bounds__(256) void k_xw(const float* __restrict__ x,
                                            const int* __restrict__ rmap,
                                            ushort* __restrict__ xw) {
  int gid = blockIdx.x * 256 + threadIdx.x;   // 16*6*3136 exact
  int p  = gid % NPF;
  int cc = (gid / NPF) % 6;
  int b  = gid / (6 * NPF);
  int sp = rmap[p];
  const float* xs = x + (size_t)b * DIM * NPF + (size_t)(cc * 64) * NPF + sp;
  ushort* xd = xw + ((size_t)b * NPF + p) * DIM + cc * 64;
  for (int c0 = 0; c0 < 64; c0 += 8) {
    us8 u;
#pragma unroll
    for (int i = 0; i < 8; ++i) u[i] = tob(xs[(size_t)(c0 + i) * NPF]);
    *(us8*)&xd[c0] = u;
  }
}

// ---------------- QKV GEMM: 128x128 tile; q/k -> qk[b][p][768], v -> vt ------
__global__ __launch_bounds__(256) void k_qkv_pm(const ushort* __restrict__ xw,
                                                const ushort* __restrict__ wqb,
                                                ushort* __restrict__ qk,
                                                ushort* __restrict__ vt) {
  __shared__ __align__(16) ushort sA[2][128 * 40];
  __shared__ __align__(16) ushort sB[2][128 * 40];
  int t   = threadIdx.x;
  int bid = blockIdx.x;
  int swz = (bid & 7) * 450 + (bid >> 3);   // 3600 = 8*450, bijective
  int o0  = (swz % 9) * 128;
  int pbt = swz / 9;
  int p0  = (pbt % 25) * 128;
  int b   = pbt / 25;

  int lane = t & 63, w = t >> 6;
  int wm = w >> 1, wn = w & 1;
  int l15 = lane & 15, l4 = lane >> 4;

  int ra0 = t >> 2,          ca0 = (t & 3) * 8;
  int ra1 = (t + 256) >> 2,  ca1 = ((t + 256) & 3) * 8;
  const ushort* apt0 = wqb + (size_t)(o0 + ra0) * DIM + ca0;
  const ushort* apt1 = wqb + (size_t)(o0 + ra1) * DIM + ca1;
  int pr0 = p0 + ra0; if (pr0 >= NPF) pr0 = NPF - 1;
  int pr1 = p0 + ra1; if (pr1 >= NPF) pr1 = NPF - 1;
  const ushort* bpt0 = xw + ((size_t)b * NPF + pr0) * DIM + ca0;
  const ushort* bpt1 = xw + ((size_t)b * NPF + pr1) * DIM + ca1;

  struct Stage { us8 a0, a1, b0, b1; };
  Stage st0, st1;

#define QLOAD(S, K0)                                    \
  do {                                                  \
    (S).a0 = *(const us8*)&apt0[(K0)];                  \
    (S).a1 = *(const us8*)&apt1[(K0)];                  \
    (S).b0 = *(const us8*)&bpt0[(K0)];                  \
    (S).b1 = *(const us8*)&bpt1[(K0)];                  \
  } while (0)
#define QWRITE(S, BUF)                                  \
  do {                                                  \
    *(us8*)&sA[(BUF)][ra0 * 40 + ca0] = (S).a0;         \
    *(us8*)&sA[(BUF)][ra1 * 40 + ca1] = (S).a1;         \
    *(us8*)&sB[(BUF)][ra0 * 40 + ca0] = (S).b0;         \
    *(us8*)&sB[(BUF)][ra1 * 40 + ca1] = (S).b1;         \
  } while (0)

  f32x4 acc[4][4] = {};

  QLOAD(st0, 0);
  QWRITE(st0, 0);
  QLOAD(st1, 32);

#pragma unroll
  for (int ks = 0; ks < 12; ++ks) {
    SOFT_BARRIER();
    if (ks < 10) {
      if ((ks & 1) == 0) QLOAD(st0, (ks + 2) * 32);
      else               QLOAD(st1, (ks + 2) * 32);
    }
    int cur = ks & 1;
    short8 af[4], bfr[4];
#pragma unroll
    for (int mi = 0; mi < 4; ++mi)
      af[mi] = *(const short8*)&sA[cur][(wm * 64 + mi * 16 + l15) * 40 + l4 * 8];
#pragma unroll
    for (int ni = 0; ni < 4; ++ni)
      bfr[ni] = *(const short8*)&sB[cur][(wn * 64 + ni * 16 + l15) * 40 + l4 * 8];
#pragma unroll
    for (int mi = 0; mi < 4; ++mi)
#pragma unroll
      for (int ni = 0; ni < 4; ++ni)
        acc[mi][ni] = MFMA(af[mi], bfr[ni], acc[mi][ni], 0, 0, 0);
    if (ks < 11) {
      if ((ks & 1) == 0) QWRITE(st1, 1);
      else               QWRITE(st0, 0);
    }
  }
#undef QLOAD
#undef QWRITE

  if (o0 < 768) {
#pragma unroll
    for (int mi = 0; mi < 4; ++mi)
#pragma unroll
      for (int ni = 0; ni < 4; ++ni) {
        int p = p0 + wn * 64 + ni * 16 + l15;
        if (p < NPF) {
          us4 u;
#pragma unroll
          for (int r = 0; r < 4; ++r) u[r] = tob(acc[mi][ni][r]);
          *(us4*)&qk[((size_t)b * NPF + p) * 768 + o0 + wm * 64 + mi * 16 + (l4 << 2)] = u;
        }
      }
  } else {
    int c0 = o0 - 768 + wm * 64;
#pragma unroll
    for (int mi = 0; mi < 4; ++mi)
#pragma unroll
      for (int ni = 0; ni < 4; ++ni) {
        int p = p0 + wn * 64 + ni * 16 + l15;
        if (p < NPF) {
#pragma unroll
          for (int r = 0; r < 4; ++r) {
            int c = c0 + mi * 16 + (l4 << 2) + r;
            vt[((size_t)b * DIM + c) * NPF + p] = tob(acc[mi][ni][r]);
          }
        }
      }
  }
}

// ---------------- attention: 2 windows/wave pipeline, exp2-softmax ----------
// Wave = head; each wave processes windows wp*2 and wp*2+1. Q/K loads for BOTH
// issued up front so pair-1 latency hides under pair-0 compute.
__global__ __launch_bounds__(256) void k_attn_pm(ushort* __restrict__ qk,
                                                 const ushort* __restrict__ vt,
                                                 const float* __restrict__ bias) {
  __shared__ __align__(16) ushort pab[4][64 * 72];   // 36864 B

  int t = threadIdx.x;
  int lane = t & 63, wv = t >> 6;
  int bid = blockIdx.x;
  int swz = (bid & 7) * 192 + (bid >> 3);   // 1536 = 8*192, bijective
  int hg = swz % 3, wp = swz / 3;           // wp in [0,512)
  int h = hg * 4 + wv;
  ushort* pa = pab[wv];
  int l15 = lane & 15, l4 = lane >> 4;

  ushort* qrow_[2];
  const ushort* vrow_[2];
#pragma unroll
  for (int pp = 0; pp < 2; ++pp) {
    int wb = wp * 2 + pp;
    int b = wb >> 6;
    int w49 = (wb & 63) * NPIX;
    qrow_[pp] = qk + ((size_t)b * NPF + w49) * 768 + h * HD;
    vrow_[pp] = vt + ((size_t)b * DIM + h * HD) * NPF + w49;
  }

  // issue Q/K loads for BOTH pairs up front
  short8 af[2][4], bfr[2][4];
#pragma unroll
  for (int pp = 0; pp < 2; ++pp) {
#pragma unroll
    for (int mi = 0; mi < 4; ++mi) {
      int rq = mi * 16 + l15; if (rq > 48) rq = 48;
      af[pp][mi] = *(const short8*)&qrow_[pp][(size_t)rq * 768 + l4 * 8];
    }
#pragma unroll
    for (int ni = 0; ni < 4; ++ni) {
      int rk = ni * 16 + l15; if (rk > 48) rk = 48;
      bfr[pp][ni] = *(const short8*)&qrow_[pp][(size_t)rk * 768 + DIM + l4 * 8];
    }
  }

  const float c1 = 0.25506807186087050f;   // scale * log2(e)
  const float* bh = bias + h * NPIX * NPIX;

#pragma unroll
  for (int pp = 0; pp < 2; ++pp) {
    f32x4 acc[4][4] = {};
#pragma unroll
    for (int mi = 0; mi < 4; ++mi)
#pragma unroll
      for (int ni = 0; ni < 4; ++ni)
        acc[mi][ni] = MFMA(af[pp][mi], bfr[pp][ni], acc[mi][ni], 0, 0, 0);

    // V loads for this pair (latency hides under softmax below)
    short8 vf[2][2];
#pragma unroll
    for (int ks = 0; ks < 2; ++ks)
#pragma unroll
      for (int nd = 0; nd < 2; ++nd)
        vf[ks][nd] = *(const short8*)&vrow_[pp][(size_t)(nd * 16 + l15) * NPF + ks * 32 + l4 * 8];

    float sm[16];
#pragma unroll
    for (int mi = 0; mi < 4; ++mi)
#pragma unroll
      for (int r = 0; r < 4; ++r) {
        int n = mi * 16 + (l4 << 2) + r;
        float s = 0.f;
#pragma unroll
        for (int ni = 0; ni < 4; ++ni) {
          int m = ni * 16 + l15;
          float e = (m < NPIX && n < NPIX)
                      ? exp2f(fmaf(acc[mi][ni][r], c1, bh[n * NPIX + m]))
                      : 0.f;
          acc[mi][ni][r] = e;
          s += e;
        }
        sm[mi * 4 + r] = s;
      }
#pragma unroll
    for (int i = 1; i < 16; i <<= 1)
#pragma unroll
      for (int j = 0; j < 16; ++j) sm[j] += __shfl_xor(sm[j], i);

#pragma unroll
    for (int mi = 0; mi < 4; ++mi)
#pragma unroll
      for (int r = 0; r < 4; ++r) {
        float ri = 1.f / sm[mi * 4 + r];
        int n = mi * 16 + (l4 << 2) + r;
#pragma unroll
        for (int ni = 0; ni < 4; ++ni)
          pa[n * 72 + ni * 16 + l15] = tob(acc[mi][ni][r] * ri);
      }

    f32x4 yac[4][2] = {};
#pragma unroll
    for (int ks = 0; ks < 2; ++ks) {
      short8 pf[4];
#pragma unroll
      for (int mi = 0; mi < 4; ++mi)
        pf[mi] = *(const short8*)&pa[(mi * 16 + l15) * 72 + ks * 32 + l4 * 8];
#pragma unroll
      for (int mi = 0; mi < 4; ++mi)
#pragma unroll
        for (int nd = 0; nd < 2; ++nd)
          yac[mi][nd] = MFMA(pf[mi], vf[ks][nd], yac[mi][nd], 0, 0, 0);
    }

#pragma unroll
    for (int mi = 0; mi < 4; ++mi)
#pragma unroll
      for (int nd = 0; nd < 2; ++nd)
#pragma unroll
        for (int r = 0; r < 4; ++r)
          pa[(mi * 16 + (l4 << 2) + r) * 72 + nd * 16 + l15] = tob(yac[mi][nd][r]);
    asm volatile("s_waitcnt lgkmcnt(0)" ::: "memory");
    if (lane < NPIX) {
#pragma unroll
      for (int s = 0; s < 4; ++s)
        *(us8*)&qrow_[pp][(size_t)lane * 768 + s * 8] = *(const us8*)&pa[lane * 72 + s * 8];
    }
  }
}

// ---------------- proj GEMM: Y from qk (stride 768) -------------------------
__global__ __launch_bounds__(256) void k_proj_pm(const ushort* __restrict__ qk,
                                                 const ushort* __restrict__ wpb,
                                                 float* __restrict__ out) {
  __shared__ __align__(16) ushort sA[2][128 * 40];
  __shared__ __align__(16) ushort sB[2][128 * 40];
  __shared__ int srm[128];
  int t   = threadIdx.x;
  int bid = blockIdx.x;
  int swz = (bid & 7) * 150 + (bid >> 3);   // 1200 = 8*150
  int o0  = (swz % 3) * 128;
  int pb  = swz / 3;
  int p0  = (pb % 25) * 128;
  int b   = pb / 25;
  if (t < 128) {
    int pg = p0 + t;
    if (pg >= NPF) pg = 0;
    int si = (pg / IMG + 53) % IMG, sj = (pg % IMG + 53) % IMG;
    srm[t] = ((si / WIN) * 8 + sj / WIN) * NPIX + (si % WIN) * WIN + (sj % WIN);
  }
  __syncthreads();

  int lane = t & 63, w = t >> 6;
  int wm = w >> 1, wn = w & 1;
  int l15 = lane & 15, l4 = lane >> 4;

  int ra0 = t >> 2,          ca0 = (t & 3) * 8;
  int ra1 = (t + 256) >> 2,  ca1 = ((t + 256) & 3) * 8;
  const ushort* apt0 = wpb + (size_t)(o0 + ra0) * DIM + ca0;
  const ushort* apt1 = wpb + (size_t)(o0 + ra1) * DIM + ca1;
  const ushort* bpt0 = qk + ((size_t)b * NPF + srm[ra0]) * 768 + ca0;
  const ushort* bpt1 = qk + ((size_t)b * NPF + srm[ra1]) * 768 + ca1;

  struct Stage { us8 a0, a1, b0, b1; };
  Stage st0, st1;

#define PLOAD(S, K0)                                    \
  do {                                                  \
    (S).a0 = *(const us8*)&apt0[(K0)];                  \
    (S).a1 = *(const us8*)&apt1[(K0)];                  \
    (S).b0 = *(const us8*)&bpt0[(K0)];                  \
    (S).b1 = *(const us8*)&bpt1[(K0)];                  \
  } while (0)
#define PWRITE(S, BUF)                                  \
  do {                                                  \
    *(us8*)&sA[(BUF)][ra0 * 40 + ca0] = (S).a0;         \
    *(us8*)&sA[(BUF)][ra1 * 40 + ca1] = (S).a1;         \
    *(us8*)&sB[(BUF)][ra0 * 40 + ca0] = (S).b0;         \
    *(us8*)&sB[(BUF)][ra1 * 40 + ca1] = (S).b1;         \
  } while (0)

  f32x4 acc[4][4] = {};

  PLOAD(st0, 0);
  PWRITE(st0, 0);
  PLOAD(st1, 32);

#pragma unroll
  for (int ks = 0; ks < 12; ++ks) {
    SOFT_BARRIER();
    if (ks < 10) {
      if ((ks & 1) == 0) PLOAD(st0, (ks + 2) * 32);
      else               PLOAD(st1, (ks + 2) * 32);
    }
    int cur = ks & 1;
    short8 af[4], bfr[4];
#pragma unroll
    for (int mi = 0; mi < 4; ++mi)
      af[mi] = *(const short8*)&sA[cur][(wm * 64 + mi * 16 + l15) * 40 + l4 * 8];
#pragma unroll
    for (int ni = 0; ni < 4; ++ni)
      bfr[ni] = *(const short8*)&sB[cur][(wn * 64 + ni * 16 + l15) * 40 + l4 * 8];
#pragma unroll
    for (int mi = 0; mi < 4; ++mi)
#pragma unroll
      for (int ni = 0; ni < 4; ++ni)
        acc[mi][ni] = MFMA(af[mi], bfr[ni], acc[mi][ni], 0, 0, 0);
    if (ks < 11) {
      if ((ks & 1) == 0) PWRITE(st1, 1);
      else               PWRITE(st0, 0);
    }
  }
#undef PLOAD
#undef PWRITE

  for (int mi = 0; mi < 4; ++mi)
    for (int ni = 0; ni < 4; ++ni)
      for (int r = 0; r < 4; ++r) {
        int o = o0 + wm * 64 + mi * 16 + (l4 << 2) + r;
        int p = p0 + wn * 64 + ni * 16 + l15;
        if (p < NPF)
          out[((size_t)b * DIM + o) * NPF + p] = acc[mi][ni][r];
      }
}

extern "C" void kernel_launch(void* const* d_in, const int* in_sizes, int n_in,
                              void* d_out, int out_size, void* d_ws, size_t ws_size,
                              hipStream_t stream) {
  const float* x     = (const float*)d_in[0];
  const float* wqkv  = (const float*)d_in[1];
  const float* wproj = (const float*)d_in[2];
  const float* cpb   = (const float*)d_in[3];
  float* out = (float*)d_out;

  char* ws = (char*)d_ws;
  float* bias = (float*)ws;                       // 115248 B
  int*   rmap = (int*)(ws + 115712);              // -> 131072
  ushort* wqb = (ushort*)(ws + 131072);           // 884736 B
  ushort* wpb = (ushort*)(ws + 1015808);          // 294912 B -> 1310720
  const size_t QK_B = (size_t)16 * NPF * 768 * 2; // 77,070,336
  const size_t VT_B = (size_t)16 * DIM * NPF * 2; // 38,535,168
  ushort* qk = (ushort*)(ws + 1310720);
  ushort* vt = (ushort*)(ws + 1310720 + QK_B);
  ushort* xw = (ushort*)(ws + 1310720 + QK_B + VT_B);  // ends 155,451,392 (proven)

  hipLaunchKernelGGL(k_bias, dim3(113), dim3(256), 0, stream, cpb, bias);
  hipLaunchKernelGGL(k_rmap, dim3(13), dim3(256), 0, stream, rmap);
  hipLaunchKernelGGL(k_wcvt, dim3(288), dim3(256), 0, stream, wqkv, wproj, wqb, wpb);
  hipLaunchKernelGGL(k_xw, dim3(1176), dim3(256), 0, stream, x, rmap, xw);
  hipLaunchKernelGGL(k_qkv_pm, dim3(3600), dim3(256), 0, stream, xw, wqb, qk, vt);
  hipLaunchKernelGGL(k_attn_pm, dim3(1536), dim3(256), 0, stream, qk, vt, bias);
  hipLaunchKernelGGL(k_proj_pm, dim3(1200), dim3(256), 0, stream, qk, wpb, out);
}